// Round 3
// baseline (116.221 us; speedup 1.0000x reference)
//
#include <hip/hip_runtime.h>

#define IMG_W 2048
#define NUM_NODES 255
#define NLEAF 128
#define DEPTH 7
#define RS 68     // padded LDS row stride (floats)
#define NBLK 256  // fusedK grid: one block per CU, co-resident by construction
#define NUPD 16   // blocks that perform the fused node-update tail

// DPP xor-butterfly add over 16-lane groups (VALU pipe). Butterfly partners add
// identical pairs -> all 16 lanes end bit-identical.
template<int CTRL>
__device__ __forceinline__ float dpp_add(float x) {
    int v = __builtin_amdgcn_update_dpp(0, __float_as_int(x), CTRL, 0xF, 0xF, true);
    return x + __int_as_float(v);
}
__device__ __forceinline__ float group16_sum(float x) {
    x = dpp_add<0xB1>(x);   // quad_perm [1,0,3,2]  : xor 1
    x = dpp_add<0x4E>(x);   // quad_perm [2,3,0,1]  : xor 2
    x = dpp_add<0x141>(x);  // row_half_mirror      : xor 7
    x = dpp_add<0x128>(x);  // row_ror:8            : xor 8
    return x;
}

// ---- K1: 4-way interleaved descent + LDS accumulate + fused node update ----
// Cost model (R0-R2): 2x 43us harness poison fills are fixed; addressable ~20us
// = fusedK ~13.5 + updateK ~2.5 + memset ~2 + gaps ~3. This round: fuse updateK
// in via arrival counter (saves a dispatch+gap) and fix the 8-way bank conflict
// in the Sl accumulate (Sl element layout transposed: e=4q+j stored at j*16+q).
__global__ __launch_bounds__(1024, 4) void fusedK(const float* __restrict__ img,
                                                  const float* __restrict__ nodes,
                                                  float* __restrict__ leaf_out,
                                                  float* __restrict__ S,
                                                  unsigned* __restrict__ cnt,
                                                  unsigned* __restrict__ fdone,
                                                  float* __restrict__ out_nodes)
{
    __shared__ float nds[NUM_NODES * RS];   // 69360 B (reused as S-stage in tail)
    __shared__ float Sl[NLEAF * RS];        // 34816 B
    __shared__ unsigned cntl[NLEAF];

    const int t = threadIdx.x;
    const int b = blockIdx.x;
    const int g = t >> 4;          // patch-group 0..63
    const int q = t & 15;          // quad within patch (elements 4q..4q+3)
    const int q4 = q * 4;

    for (int i = t; i < NLEAF * RS; i += 1024) Sl[i] = 0.0f;
    if (t < NLEAF) cntl[t] = 0u;

    // fill node table (padded rows)
    const float4* ng = (const float4*)nodes;
    for (int i = t; i < NUM_NODES * 16; i += 1024) {
        *(float4*)&nds[(i >> 4) * RS + (i & 15) * 4] = ng[i];
    }

    // prefetch 4 chunks' patch quads (element e=4q+j -> pixel (q>>1, (q&1)*4+j))
    float4 xv0, xv1, xv2, xv3;
    {
        const int roff = (q >> 1), coff = (q & 1) * 4;
        int p = b * 256 + g;
        xv0 = *(const float4*)(img + (size_t)((p >> 8) * 8 + roff) * IMG_W + (p & 255) * 8 + coff);
        p += 64;
        xv1 = *(const float4*)(img + (size_t)((p >> 8) * 8 + roff) * IMG_W + (p & 255) * 8 + coff);
        p += 64;
        xv2 = *(const float4*)(img + (size_t)((p >> 8) * 8 + roff) * IMG_W + (p & 255) * 8 + coff);
        p += 64;
        xv3 = *(const float4*)(img + (size_t)((p >> 8) * 8 + roff) * IMG_W + (p & 255) * 8 + coff);
    }
    __syncthreads();

    // 4 interleaved descents
    int cur0 = 0, cur1 = 0, cur2 = 0, cur3 = 0;
    #pragma unroll
    for (int lvl = 0; lvl < DEPTH; ++lvl) {
        const int ca = 2 * cur0 + 1;
        const int cb = 2 * cur1 + 1;
        const int cc = 2 * cur2 + 1;
        const int cd = 2 * cur3 + 1;
        const float* pa = &nds[ca * RS + q4];
        const float* pb = &nds[cb * RS + q4];
        const float* pc = &nds[cc * RS + q4];
        const float* pd = &nds[cd * RS + q4];
        // issue all 8 reads; compiler batches them before one lgkmcnt wait
        const float4 A0 = *(const float4*)(pa);
        const float4 B0 = *(const float4*)(pa + RS);
        const float4 A1 = *(const float4*)(pb);
        const float4 B1 = *(const float4*)(pb + RS);
        const float4 A2 = *(const float4*)(pc);
        const float4 B2 = *(const float4*)(pc + RS);
        const float4 A3 = *(const float4*)(pd);
        const float4 B3 = *(const float4*)(pd + RS);

        float d, s0, s1;
        // chunk 0
        s0 = 0.f; s1 = 0.f;
        d = A0.x - xv0.x; s0 = fmaf(d, d, s0);  d = B0.x - xv0.x; s1 = fmaf(d, d, s1);
        d = A0.y - xv0.y; s0 = fmaf(d, d, s0);  d = B0.y - xv0.y; s1 = fmaf(d, d, s1);
        d = A0.z - xv0.z; s0 = fmaf(d, d, s0);  d = B0.z - xv0.z; s1 = fmaf(d, d, s1);
        d = A0.w - xv0.w; s0 = fmaf(d, d, s0);  d = B0.w - xv0.w; s1 = fmaf(d, d, s1);
        cur0 = (group16_sum(s1 - s0) < 0.0f) ? (ca + 1) : ca;   // d1<d0 picks c1 (strict)
        // chunk 1
        s0 = 0.f; s1 = 0.f;
        d = A1.x - xv1.x; s0 = fmaf(d, d, s0);  d = B1.x - xv1.x; s1 = fmaf(d, d, s1);
        d = A1.y - xv1.y; s0 = fmaf(d, d, s0);  d = B1.y - xv1.y; s1 = fmaf(d, d, s1);
        d = A1.z - xv1.z; s0 = fmaf(d, d, s0);  d = B1.z - xv1.z; s1 = fmaf(d, d, s1);
        d = A1.w - xv1.w; s0 = fmaf(d, d, s0);  d = B1.w - xv1.w; s1 = fmaf(d, d, s1);
        cur1 = (group16_sum(s1 - s0) < 0.0f) ? (cb + 1) : cb;
        // chunk 2
        s0 = 0.f; s1 = 0.f;
        d = A2.x - xv2.x; s0 = fmaf(d, d, s0);  d = B2.x - xv2.x; s1 = fmaf(d, d, s1);
        d = A2.y - xv2.y; s0 = fmaf(d, d, s0);  d = B2.y - xv2.y; s1 = fmaf(d, d, s1);
        d = A2.z - xv2.z; s0 = fmaf(d, d, s0);  d = B2.z - xv2.z; s1 = fmaf(d, d, s1);
        d = A2.w - xv2.w; s0 = fmaf(d, d, s0);  d = B2.w - xv2.w; s1 = fmaf(d, d, s1);
        cur2 = (group16_sum(s1 - s0) < 0.0f) ? (cc + 1) : cc;
        // chunk 3
        s0 = 0.f; s1 = 0.f;
        d = A3.x - xv3.x; s0 = fmaf(d, d, s0);  d = B3.x - xv3.x; s1 = fmaf(d, d, s1);
        d = A3.y - xv3.y; s0 = fmaf(d, d, s0);  d = B3.y - xv3.y; s1 = fmaf(d, d, s1);
        d = A3.z - xv3.z; s0 = fmaf(d, d, s0);  d = B3.z - xv3.z; s1 = fmaf(d, d, s1);
        d = A3.w - xv3.w; s0 = fmaf(d, d, s0);  d = B3.w - xv3.w; s1 = fmaf(d, d, s1);
        cur3 = (group16_sum(s1 - s0) < 0.0f) ? (cd + 1) : cd;
    }

    if (q == 0) {
        leaf_out[b * 256 + g]       = (float)cur0;
        leaf_out[b * 256 + 64 + g]  = (float)cur1;
        leaf_out[b * 256 + 128 + g] = (float)cur2;
        leaf_out[b * 256 + 192 + g] = (float)cur3;
        atomicAdd(&cntl[cur0 - 127], 1u);
        atomicAdd(&cntl[cur1 - 127], 1u);
        atomicAdd(&cntl[cur2 - 127], 1u);
        atomicAdd(&cntl[cur3 - 127], 1u);
    }

    // accumulate quads into leaf rows, TRANSPOSED element layout: e=4q+j stored
    // at phys j*16+q. Bank of one atomic (fixed j) = (4L+16j+q)%32: 16 q-values
    // span 16 consecutive banks -> ~2-way (free) vs old 8-way on 8 banks.
    {
        float* base = &Sl[(cur0 - 127) * RS + q];
        atomicAdd(base +  0, xv0.x); atomicAdd(base + 16, xv0.y);
        atomicAdd(base + 32, xv0.z); atomicAdd(base + 48, xv0.w);
        base = &Sl[(cur1 - 127) * RS + q];
        atomicAdd(base +  0, xv1.x); atomicAdd(base + 16, xv1.y);
        atomicAdd(base + 32, xv1.z); atomicAdd(base + 48, xv1.w);
        base = &Sl[(cur2 - 127) * RS + q];
        atomicAdd(base +  0, xv2.x); atomicAdd(base + 16, xv2.y);
        atomicAdd(base + 32, xv2.z); atomicAdd(base + 48, xv2.w);
        base = &Sl[(cur3 - 127) * RS + q];
        atomicAdd(base +  0, xv3.x); atomicAdd(base + 16, xv3.y);
        atomicAdd(base + 32, xv3.z); atomicAdd(base + 48, xv3.w);
    }
    __syncthreads();

    // flush block sums to global S (invert the transposed layout; rotate start
    // per block to decorrelate inter-block atomic collisions; S pre-zeroed)
    for (int ii = t; ii < NLEAF * 64; ii += 1024) {
        const int i = (ii + b * 64) & (NLEAF * 64 - 1);
        const int e = i & 63;
        const float v = Sl[(i >> 6) * RS + (e & 3) * 16 + (e >> 2)];
        if (v != 0.0f) atomicAdd(&S[i], v);
    }
    if (t < NLEAF && cntl[t] != 0u) atomicAdd(&cnt[t], cntl[t]);

    // ---- arrival + fused node update (replaces the separate updateK launch) --
    __syncthreads();   // barrier drains vmcnt -> this block's atomics are visible
    if (t == 0) {
        __threadfence();
        __hip_atomic_fetch_add(fdone, 1u, __ATOMIC_RELEASE, __HIP_MEMORY_SCOPE_AGENT);
    }
    if (b >= NUPD) return;   // only blocks 0..15 spin: deadlock-safe on any partition

    if (t == 0) {
        while (__hip_atomic_load(fdone, __ATOMIC_ACQUIRE, __HIP_MEMORY_SCOPE_AGENT) != NBLK) {}
    }
    __syncthreads();

    // stage S (32KB) + cnt into reused LDS via agent-scope loads (coherent point)
    float* Ss = nds;            // 8192 floats
    float* cs = nds + 8192;     // 128 floats
    for (int i = t; i < NLEAF * 64; i += 1024)
        Ss[i] = __hip_atomic_load(&S[i], __ATOMIC_RELAXED, __HIP_MEMORY_SCOPE_AGENT);
    if (t < NLEAF)
        cs[t] = (float)__hip_atomic_load(&cnt[t], __ATOMIC_RELAXED, __HIP_MEMORY_SCOPE_AGENT);
    __syncthreads();

    // 16 nodes per block, one output element per thread (wave reads Ss[L*64+k],
    // k=0..63 consecutive -> conflict-free)
    const int n = b * 16 + (t >> 6);
    const int k = t & 63;
    if (n >= NUM_NODES) return;
    const float nd = nodes[n * 64 + k];
    float o;
    if (n == 0) {
        o = nd;
    } else {
        const int pos = n + 1;                 // 1-based heap index
        const int Ln = 31 - __clz(pos);        // node level, 1..7
        float su = 0.f, sc = 0.f;
        #pragma unroll 8
        for (int L = 0; L < NLEAF; ++L) {
            const int a = (128 + L) >> (7 - Ln);   // leaf's ancestor at level Ln
            const int x = pos ^ a;
            const int state = (x == 0) ? Ln : (Ln - (31 - __clz(x)) - 1);
            const float lr = 0.3f * ((float)(1 << state) * (1.0f / 128.0f));
            su = fmaf(lr, Ss[L * 64 + k], su);
            sc = fmaf(lr, cs[L], sc);
        }
        const float invP = 1.0f / 65536.0f;
        o = nd + su * invP - (sc * invP) * nd;
    }
    out_nodes[n * 64 + k] = o;
}

extern "C" void kernel_launch(void* const* d_in, const int* in_sizes, int n_in,
                              void* d_out, int out_size, void* d_ws, size_t ws_size,
                              hipStream_t stream)
{
    const float* img   = (const float*)d_in[0];   // 2048*2048 f32
    const float* nodes = (const float*)d_in[1];   // 255*64 f32

    float* out_nodes = (float*)d_out;                 // 255*64
    float* out_leaf  = out_nodes + NUM_NODES * 64;    // 65536 (leaf index as f32)

    float*    S     = (float*)d_ws;                   // 128*64 f32
    unsigned* cnt   = (unsigned*)(S + NLEAF * 64);    // 128 u32
    unsigned* fdone = cnt + NLEAF;                    // 1 u32 arrival counter

    hipMemsetAsync(d_ws, 0,
                   (NLEAF * 64) * sizeof(float) + NLEAF * sizeof(unsigned) + 16,
                   stream);
    fusedK<<<NBLK, 1024, 0, stream>>>(img, nodes, out_leaf, S, cnt, fdone, out_nodes);
}

// Round 4
// 106.727 us; speedup vs baseline: 1.0890x; 1.0890x over previous
//
#include <hip/hip_runtime.h>

#define IMG_W 2048
#define NUM_NODES 255
#define NLEAF 128
#define DEPTH 7
#define RS 68   // padded LDS row stride (floats); 16B-chunk bank-group = (row+q)%8 -> balanced

// DPP xor-butterfly add over 16-lane groups (VALU pipe). Butterfly partners add
// identical pairs -> all 16 lanes end bit-identical.
template<int CTRL>
__device__ __forceinline__ float dpp_add(float x) {
    int v = __builtin_amdgcn_update_dpp(0, __float_as_int(x), CTRL, 0xF, 0xF, true);
    return x + __int_as_float(v);
}
__device__ __forceinline__ float group16_sum(float x) {
    x = dpp_add<0xB1>(x);   // quad_perm [1,0,3,2]  : xor 1
    x = dpp_add<0x4E>(x);   // quad_perm [2,3,0,1]  : xor 2
    x = dpp_add<0x141>(x);  // row_half_mirror      : xor 7
    x = dpp_add<0x128>(x);  // row_ror:8            : xor 8
    return x;
}

// ---- K1: 4-way interleaved descent (16 lanes/patch) + LDS-atomic accumulate --
// 256 blocks x 1024 thr, ~105 KB LDS -> 1 block/CU, 16 waves/CU.
// R3 post-mortem: spin-wait fusion of the update tail REGRESSED (+10us; tail on
// 16 CUs instead of 64, rocprof replay pathological). Back to 3 dispatches.
// This round keeps only R3's isolated bank-conflict fix: Sl element e=4q+j is
// stored TRANSPOSED at phys j*16+q, so each atomic's 16 lanes span 16
// consecutive banks (~2-way, free per m136) instead of stride-4 on 8 banks.
__global__ __launch_bounds__(1024, 4) void fusedK(const float* __restrict__ img,
                                                  const float* __restrict__ nodes,
                                                  float* __restrict__ leaf_out,
                                                  float* __restrict__ S,
                                                  unsigned* __restrict__ cnt)
{
    __shared__ float nds[NUM_NODES * RS];   // 69360 B
    __shared__ float Sl[NLEAF * RS];        // 34816 B
    __shared__ unsigned cntl[NLEAF];

    const int t = threadIdx.x;
    const int b = blockIdx.x;
    const int g = t >> 4;          // patch-group 0..63
    const int q = t & 15;          // quad within patch (elements 4q..4q+3)
    const int q4 = q * 4;

    for (int i = t; i < NLEAF * RS; i += 1024) Sl[i] = 0.0f;
    if (t < NLEAF) cntl[t] = 0u;

    // fill node table (padded rows)
    const float4* ng = (const float4*)nodes;
    for (int i = t; i < NUM_NODES * 16; i += 1024) {
        *(float4*)&nds[(i >> 4) * RS + (i & 15) * 4] = ng[i];
    }

    // prefetch 4 chunks' patch quads (element e=4q+j -> pixel (q>>1, (q&1)*4+j))
    float4 xv0, xv1, xv2, xv3;
    {
        const int roff = (q >> 1), coff = (q & 1) * 4;
        int p = b * 256 + g;
        xv0 = *(const float4*)(img + (size_t)((p >> 8) * 8 + roff) * IMG_W + (p & 255) * 8 + coff);
        p += 64;
        xv1 = *(const float4*)(img + (size_t)((p >> 8) * 8 + roff) * IMG_W + (p & 255) * 8 + coff);
        p += 64;
        xv2 = *(const float4*)(img + (size_t)((p >> 8) * 8 + roff) * IMG_W + (p & 255) * 8 + coff);
        p += 64;
        xv3 = *(const float4*)(img + (size_t)((p >> 8) * 8 + roff) * IMG_W + (p & 255) * 8 + coff);
    }
    __syncthreads();

    // 4 interleaved descents
    int cur0 = 0, cur1 = 0, cur2 = 0, cur3 = 0;
    #pragma unroll
    for (int lvl = 0; lvl < DEPTH; ++lvl) {
        const int ca = 2 * cur0 + 1;
        const int cb = 2 * cur1 + 1;
        const int cc = 2 * cur2 + 1;
        const int cd = 2 * cur3 + 1;
        const float* pa = &nds[ca * RS + q4];
        const float* pb = &nds[cb * RS + q4];
        const float* pc = &nds[cc * RS + q4];
        const float* pd = &nds[cd * RS + q4];
        // issue all 8 reads; compiler batches them before one lgkmcnt wait
        const float4 A0 = *(const float4*)(pa);
        const float4 B0 = *(const float4*)(pa + RS);
        const float4 A1 = *(const float4*)(pb);
        const float4 B1 = *(const float4*)(pb + RS);
        const float4 A2 = *(const float4*)(pc);
        const float4 B2 = *(const float4*)(pc + RS);
        const float4 A3 = *(const float4*)(pd);
        const float4 B3 = *(const float4*)(pd + RS);

        float d, s0, s1;
        // chunk 0
        s0 = 0.f; s1 = 0.f;
        d = A0.x - xv0.x; s0 = fmaf(d, d, s0);  d = B0.x - xv0.x; s1 = fmaf(d, d, s1);
        d = A0.y - xv0.y; s0 = fmaf(d, d, s0);  d = B0.y - xv0.y; s1 = fmaf(d, d, s1);
        d = A0.z - xv0.z; s0 = fmaf(d, d, s0);  d = B0.z - xv0.z; s1 = fmaf(d, d, s1);
        d = A0.w - xv0.w; s0 = fmaf(d, d, s0);  d = B0.w - xv0.w; s1 = fmaf(d, d, s1);
        cur0 = (group16_sum(s1 - s0) < 0.0f) ? (ca + 1) : ca;   // d1<d0 picks c1 (strict)
        // chunk 1
        s0 = 0.f; s1 = 0.f;
        d = A1.x - xv1.x; s0 = fmaf(d, d, s0);  d = B1.x - xv1.x; s1 = fmaf(d, d, s1);
        d = A1.y - xv1.y; s0 = fmaf(d, d, s0);  d = B1.y - xv1.y; s1 = fmaf(d, d, s1);
        d = A1.z - xv1.z; s0 = fmaf(d, d, s0);  d = B1.z - xv1.z; s1 = fmaf(d, d, s1);
        d = A1.w - xv1.w; s0 = fmaf(d, d, s0);  d = B1.w - xv1.w; s1 = fmaf(d, d, s1);
        cur1 = (group16_sum(s1 - s0) < 0.0f) ? (cb + 1) : cb;
        // chunk 2
        s0 = 0.f; s1 = 0.f;
        d = A2.x - xv2.x; s0 = fmaf(d, d, s0);  d = B2.x - xv2.x; s1 = fmaf(d, d, s1);
        d = A2.y - xv2.y; s0 = fmaf(d, d, s0);  d = B2.y - xv2.y; s1 = fmaf(d, d, s1);
        d = A2.z - xv2.z; s0 = fmaf(d, d, s0);  d = B2.z - xv2.z; s1 = fmaf(d, d, s1);
        d = A2.w - xv2.w; s0 = fmaf(d, d, s0);  d = B2.w - xv2.w; s1 = fmaf(d, d, s1);
        cur2 = (group16_sum(s1 - s0) < 0.0f) ? (cc + 1) : cc;
        // chunk 3
        s0 = 0.f; s1 = 0.f;
        d = A3.x - xv3.x; s0 = fmaf(d, d, s0);  d = B3.x - xv3.x; s1 = fmaf(d, d, s1);
        d = A3.y - xv3.y; s0 = fmaf(d, d, s0);  d = B3.y - xv3.y; s1 = fmaf(d, d, s1);
        d = A3.z - xv3.z; s0 = fmaf(d, d, s0);  d = B3.z - xv3.z; s1 = fmaf(d, d, s1);
        d = A3.w - xv3.w; s0 = fmaf(d, d, s0);  d = B3.w - xv3.w; s1 = fmaf(d, d, s1);
        cur3 = (group16_sum(s1 - s0) < 0.0f) ? (cd + 1) : cd;
    }

    if (q == 0) {
        leaf_out[b * 256 + g]       = (float)cur0;
        leaf_out[b * 256 + 64 + g]  = (float)cur1;
        leaf_out[b * 256 + 128 + g] = (float)cur2;
        leaf_out[b * 256 + 192 + g] = (float)cur3;
        atomicAdd(&cntl[cur0 - 127], 1u);
        atomicAdd(&cntl[cur1 - 127], 1u);
        atomicAdd(&cntl[cur2 - 127], 1u);
        atomicAdd(&cntl[cur3 - 127], 1u);
    }

    // accumulate quads into leaf rows, TRANSPOSED element layout: e=4q+j at
    // phys j*16+q. One atomic (fixed j): banks (4L+16j+q)%32, q=0..15 -> 16
    // consecutive banks (~2-way, free) vs old stride-4 on 8 banks (~4-8 way).
    {
        float* base = &Sl[(cur0 - 127) * RS + q];
        atomicAdd(base +  0, xv0.x); atomicAdd(base + 16, xv0.y);
        atomicAdd(base + 32, xv0.z); atomicAdd(base + 48, xv0.w);
        base = &Sl[(cur1 - 127) * RS + q];
        atomicAdd(base +  0, xv1.x); atomicAdd(base + 16, xv1.y);
        atomicAdd(base + 32, xv1.z); atomicAdd(base + 48, xv1.w);
        base = &Sl[(cur2 - 127) * RS + q];
        atomicAdd(base +  0, xv2.x); atomicAdd(base + 16, xv2.y);
        atomicAdd(base + 32, xv2.z); atomicAdd(base + 48, xv2.w);
        base = &Sl[(cur3 - 127) * RS + q];
        atomicAdd(base +  0, xv3.x); atomicAdd(base + 16, xv3.y);
        atomicAdd(base + 32, xv3.z); atomicAdd(base + 48, xv3.w);
    }
    __syncthreads();

    // flush block sums to global S (invert transposed layout; skip zeros;
    // lane-distinct addresses; S pre-zeroed)
    for (int i = t; i < NLEAF * 64; i += 1024) {
        const int e = i & 63;
        const float v = Sl[(i >> 6) * RS + (e & 3) * 16 + (e >> 2)];
        if (v != 0.0f) atomicAdd(&S[i], v);
    }
    if (t < NLEAF && cntl[t] != 0u) atomicAdd(&cnt[t], cntl[t]);
}

// ---------------- K2: node update (254x64x128 contraction) -------------------
// R2-proven: stage S (32KB) + cnt into LDS once per block; the leaf loop
// otherwise issues ~4.2M stride-256B global loads (latency-bound at low occ).
__global__ __launch_bounds__(256) void updateK(const float* __restrict__ nodes,
                                               const float* __restrict__ S,
                                               const unsigned* __restrict__ cnt,
                                               float* __restrict__ out)
{
    __shared__ float Ss[NLEAF * 64];    // 32768 B
    __shared__ float cs[NLEAF];

    const int t = threadIdx.x;
    // stage S: 2048 float4 over 256 threads = 8 each, coalesced
    #pragma unroll
    for (int i = t; i < NLEAF * 16; i += 256) {
        ((float4*)Ss)[i] = ((const float4*)S)[i];
    }
    if (t < NLEAF) cs[t] = (float)cnt[t];
    __syncthreads();

    const int gid = blockIdx.x * 256 + t;
    if (gid >= NUM_NODES * 64) return;
    const int n = gid >> 6, k = gid & 63;
    const float nd = nodes[gid];
    if (n == 0) { out[gid] = nd; return; }

    const int pos = n + 1;                 // 1-based heap index
    const int Ln = 31 - __clz(pos);        // node level, 1..7
    float su = 0.f, sc = 0.f;
    #pragma unroll 8
    for (int L = 0; L < NLEAF; ++L) {
        const int a = (128 + L) >> (7 - Ln);   // leaf's ancestor at level Ln
        const int x = pos ^ a;
        const int state = (x == 0) ? Ln : (Ln - (31 - __clz(x)) - 1);
        const float lr = 0.3f * ((float)(1 << state) * (1.0f / 128.0f));
        su = fmaf(lr, Ss[L * 64 + k], su);
        sc = fmaf(lr, cs[L], sc);
    }
    const float invP = 1.0f / 65536.0f;
    out[gid] = nd + su * invP - (sc * invP) * nd;
}

extern "C" void kernel_launch(void* const* d_in, const int* in_sizes, int n_in,
                              void* d_out, int out_size, void* d_ws, size_t ws_size,
                              hipStream_t stream)
{
    const float* img   = (const float*)d_in[0];   // 2048*2048 f32
    const float* nodes = (const float*)d_in[1];   // 255*64 f32

    float* out_nodes = (float*)d_out;                 // 255*64
    float* out_leaf  = out_nodes + NUM_NODES * 64;    // 65536 (leaf index as f32)

    float*    S   = (float*)d_ws;                     // 128*64 f32
    unsigned* cnt = (unsigned*)(S + NLEAF * 64);      // 128 u32

    hipMemsetAsync(d_ws, 0, (NLEAF * 64) * sizeof(float) + NLEAF * sizeof(unsigned), stream);
    fusedK<<<256, 1024, 0, stream>>>(img, nodes, out_leaf, S, cnt);
    updateK<<<64, 256, 0, stream>>>(nodes, S, cnt, out_nodes);
}